// Round 1
// baseline (91.609 us; speedup 1.0000x reference)
//
#include <hip/hip_runtime.h>

// Problem constants
#define TT     2048
#define NB     32
#define NL     10
#define NU     64
#define TTILE  64
#define NTTILE 32          // TT/TTILE = chunk count after in-block fold
#define NW     20          // iterated-sum words per (b,chunk,u)
#define DT2    145         // d-tile row stride (cols 144 = l=1..9 x 16; odd -> conflict-free)

// d_ws layout (bytes):
//   Bg: [uq(4)][reg(20)][lane(64)][8] bf16     = 80 KB     @ 0
//   L : [b][chunk(32)][w(20)][u(64)] fp32      = 5.24 MB   @ 128 KB
#define L_OFF  (128u * 1024u)

typedef __attribute__((ext_vector_type(8))) short short8v;   // 8 bf16
typedef __attribute__((ext_vector_type(4))) float float4v;   // MFMA C/D
typedef __attribute__((ext_vector_type(4), aligned(4))) float f4u; // unaligned float4
typedef __attribute__((address_space(3))) char lds_char;
typedef __attribute__((address_space(1))) const char g_char;

__device__ inline short f2bf(float f) {   // RNE float->bf16 raw bits
    unsigned u = __float_as_uint(f);
    u += 0x7fffu + ((u >> 16) & 1u);
    return (short)(u >> 16);
}

// ---- Chen composition (full 20-word alphabet), C = A(earlier) ∘ B(later) ----
// 0:(0) | 1:(1) 2:(2) 3:(12) | 4:(3) 5:(4) 6:(5) 7:(34) 8:(45) 9:(345)
// 10:(6) 11:(7) 12:(8) 13:(9) 14:(67) 15:(78) 16:(89) 17:(678) 18:(789) 19:(6789)
__device__ inline void chen_combine(const float* A, const float* B, float* C) {
    C[0]  = A[0] + B[0];
    C[1]  = A[1] + B[1];
    C[2]  = A[2] + B[2];
    C[3]  = A[3] + A[1]*B[2] + B[3];
    C[4]  = A[4] + B[4];
    C[5]  = A[5] + B[5];
    C[6]  = A[6] + B[6];
    C[7]  = A[7] + A[4]*B[5] + B[7];
    C[8]  = A[8] + A[5]*B[6] + B[8];
    C[9]  = A[9] + A[7]*B[6] + A[4]*B[8] + B[9];
    C[10] = A[10] + B[10];
    C[11] = A[11] + B[11];
    C[12] = A[12] + B[12];
    C[13] = A[13] + B[13];
    C[14] = A[14] + A[10]*B[11] + B[14];
    C[15] = A[15] + A[11]*B[12] + B[15];
    C[16] = A[16] + A[12]*B[13] + B[16];
    C[17] = A[17] + A[14]*B[12] + A[10]*B[15] + B[17];
    C[18] = A[18] + A[15]*B[13] + A[11]*B[16] + B[18];
    C[19] = A[19] + A[17]*B[13] + A[14]*B[16] + A[10]*B[18] + B[19];
}

// ---- chain-local Chen combiners ----
struct Chen1 {  // S0=(1) S1=(2) S2=(12)
    __device__ void operator()(const float* A, const float* B, float* C) const {
        C[2] = A[2] + A[0]*B[1] + B[2];
        C[0] = A[0] + B[0];  C[1] = A[1] + B[1];
    }
};
struct Chen2 {  // S0=(3) S1=(4) S2=(5) S3=(34) S4=(45) S5=(345)
    __device__ void operator()(const float* A, const float* B, float* C) const {
        C[5] = A[5] + A[3]*B[2] + A[0]*B[4] + B[5];
        C[3] = A[3] + A[0]*B[1] + B[3];
        C[4] = A[4] + A[1]*B[2] + B[4];
        C[0] = A[0] + B[0];  C[1] = A[1] + B[1];  C[2] = A[2] + B[2];
    }
};
struct Chen3 {  // S0..3=(6)(7)(8)(9) S4=(67) S5=(78) S6=(89) S7=(678) S8=(789) S9=(6789)
    __device__ void operator()(const float* A, const float* B, float* C) const {
        C[9] = A[9] + A[7]*B[3] + A[4]*B[6] + A[0]*B[8] + B[9];
        C[7] = A[7] + A[4]*B[2] + A[0]*B[5] + B[7];
        C[8] = A[8] + A[5]*B[3] + A[1]*B[6] + B[8];
        C[4] = A[4] + A[0]*B[1] + B[4];
        C[5] = A[5] + A[1]*B[2] + B[5];
        C[6] = A[6] + A[2]*B[3] + B[6];
        C[0] = A[0] + B[0];  C[1] = A[1] + B[1];
        C[2] = A[2] + B[2];  C[3] = A[3] + B[3];
    }
};

// Cross-lane fold of 4 sub-chunks (sub = lane>>4) in t-order via xor-16/32 tree.
template <int N, typename CH>
__device__ inline void wave_fold(float* S, int sub, CH chen) {
    float O[N], A[N], Bv[N], C[N];
#pragma unroll
    for (int w = 0; w < N; ++w) O[w] = __shfl_xor(S[w], 16);
    {
        const bool e = (sub & 1) == 0;
#pragma unroll
        for (int w = 0; w < N; ++w) { A[w] = e ? S[w] : O[w]; Bv[w] = e ? O[w] : S[w]; }
        chen(A, Bv, C);
    }
#pragma unroll
    for (int w = 0; w < N; ++w) O[w] = __shfl_xor(C[w], 32);
    {
        const bool e = (sub & 2) == 0;
#pragma unroll
        for (int w = 0; w < N; ++w) { A[w] = e ? C[w] : O[w]; Bv[w] = e ? O[w] : C[w]; }
        chen(A, Bv, S);
    }
}

// Kernel 0: K -> bf16 fragment tiles (Bg). 8 blocks only (A-prep is fused into k_gemm_scan).
__global__ __launch_bounds__(256)
void k_prep_b(const float* __restrict__ K, short* __restrict__ Bg) {
    const int tid = threadIdx.x;
    const int kb  = blockIdx.x;                 // 0..7
#pragma unroll
    for (int it = 0; it < 3; ++it) {
        const int r = it * 256 + tid;
        if (r >= 640) break;
        const int idx = kb * 640 + r;           // short8v index 0..5119
        const int lane = idx & 63, r20 = (idx >> 6) % 20, uq = (idx >> 6) / 20;
        const int l = r20 >> 1, s = r20 & 1;
        const int f0 = s * 32 + (lane >> 4) * 8;
        const int u = uq * 16 + (lane & 15);
        short8v v;
#pragma unroll
        for (int j = 0; j < 8; ++j)
            v[j] = f2bf(K[(size_t)(f0 + j) * (NL * NU) + l * NU + u]);
        *(short8v*)(Bg + (size_t)idx * 8) = v;
    }
}

// Kernel 1 (fused): DMA-stage B fragments; build A fragments (dX) in registers
// straight from x (L3-resident, 4x uq re-read absorbed by Infinity Cache);
// MFMA d = dX*K -> scan chains -> in-block Chen fold.
__global__ __launch_bounds__(256, 4)
void k_gemm_scan(const float* __restrict__ x, const short* __restrict__ Bg,
                 float* __restrict__ L) {
    __shared__ __align__(16) float sm[64 * DT2 + 64];   // 37,376 B -> 4 blocks/CU
    short* B_lds = (short*)sm;          // [20][64][8] = 20 KB (aliased by dtile later)
    float* dtile = sm;                  // post-MFMA: [t*145 + (l-1)*16 + su]
    float* w0buf = sm + 64 * DT2;       // [4][16]

    const int tid   = threadIdx.x;
    const int ttile = blockIdx.x;
    const int uq    = blockIdx.y;
    const int b     = blockIdx.z;
    const int wv    = tid >> 6, lane = tid & 63;

    // ---- async DMA stage: B 20 KB (issued first; latency hides under A build) ----
    {
        const char* gb = (const char*)(Bg + (size_t)uq * 10240);
#pragma unroll
        for (int i = 0; i < 5; ++i) {
            const int e = i * 256 + tid;
            __builtin_amdgcn_global_load_lds((g_char*)(gb + e * 16),
                                             (lds_char*)((char*)B_lds + e * 16), 16, 0, 0);
        }
    }

    // ---- A fragments in registers: dX[t][f] = x[t][f]-x[t-1][f] (f=63 -> dt const) ----
    const int   t      = wv * 16 + (lane & 15);
    const int   tb_idx = ttile * TTILE + t;         // time index within batch b
    const int   rowg   = b * TT + tb_idx;           // global row in x
    const int   f0     = (lane >> 4) * 8;           // s=0 octet: f 0..31
    const int   f1     = 32 + f0;                   // s=1 octet: f 32..63
    const float dtc    = 2.0f / (float)(TT - 1);
    const bool  zrow   = (tb_idx == 0);             // dX row 0 of each batch is zero
    const float* hi = x + (size_t)rowg * 63;
    const float* lo = (rowg == 0) ? hi : hi - 63;   // clamp: b=0,t=0 is zeroed anyway

    short8v a0, a1;
    {
        const f4u h0 = *(const f4u*)(hi + f0);
        const f4u h1 = *(const f4u*)(hi + f0 + 4);
        const f4u l0 = *(const f4u*)(lo + f0);
        const f4u l1 = *(const f4u*)(lo + f0 + 4);
#pragma unroll
        for (int j = 0; j < 4; ++j) { const float d = h0[j] - l0[j]; a0[j]     = f2bf(zrow ? 0.f : d); }
#pragma unroll
        for (int j = 0; j < 4; ++j) { const float d = h1[j] - l1[j]; a0[4 + j] = f2bf(zrow ? 0.f : d); }
    }
    if (f1 == 56) {
        // last octet touches f=63 (time channel, constant dtc); shift the hi load
        // left by 1 so we never read x[rowg*63+63] (OOB at the tensor's last row).
        const f4u h2 = *(const f4u*)(hi + 55);
        const f4u h3 = *(const f4u*)(hi + 59);
        const f4u l2 = *(const f4u*)(lo + 56);
        const f4u l3 = *(const f4u*)(lo + 60);
        float d;
        d = h2[1] - l2[0]; a1[0] = f2bf(zrow ? 0.f : d);
        d = h2[2] - l2[1]; a1[1] = f2bf(zrow ? 0.f : d);
        d = h2[3] - l2[2]; a1[2] = f2bf(zrow ? 0.f : d);
        d = h3[0] - l2[3]; a1[3] = f2bf(zrow ? 0.f : d);
        d = h3[1] - l3[0]; a1[4] = f2bf(zrow ? 0.f : d);
        d = h3[2] - l3[1]; a1[5] = f2bf(zrow ? 0.f : d);
        d = h3[3] - l3[2]; a1[6] = f2bf(zrow ? 0.f : d);
        a1[7] = f2bf(zrow ? 0.f : dtc);
    } else {
        const f4u h2 = *(const f4u*)(hi + f1);
        const f4u h3 = *(const f4u*)(hi + f1 + 4);
        const f4u l2 = *(const f4u*)(lo + f1);
        const f4u l3 = *(const f4u*)(lo + f1 + 4);
#pragma unroll
        for (int j = 0; j < 4; ++j) { const float d = h2[j] - l2[j]; a1[j]     = f2bf(zrow ? 0.f : d); }
#pragma unroll
        for (int j = 0; j < 4; ++j) { const float d = h3[j] - l3[j]; a1[4 + j] = f2bf(zrow ? 0.f : d); }
    }
    __syncthreads();    // drains B DMA (vmcnt(0) before barrier)

    // ---- MFMA: wave wv computes C rows [16wv,16wv+16) x 160 cols ----
    const short8v* B8 = (const short8v*)B_lds;
    float4v acc[10];
#pragma unroll
    for (int nt = 0; nt < 10; ++nt) {
        const short8v b0 = B8[(nt * 2 + 0) * 64 + lane];
        const short8v b1 = B8[(nt * 2 + 1) * 64 + lane];
        float4v z = {0.f, 0.f, 0.f, 0.f};
        z = __builtin_amdgcn_mfma_f32_16x16x32_bf16(a0, b0, z, 0, 0, 0);
        z = __builtin_amdgcn_mfma_f32_16x16x32_bf16(a1, b1, z, 0, 0, 0);
        acc[nt] = z;
    }

    // ---- word (0): reduce acc[0] (chain 0 never hits LDS) ----
    float s0 = acc[0][0] + acc[0][1] + acc[0][2] + acc[0][3];
    s0 += __shfl_xor(s0, 16);
    s0 += __shfl_xor(s0, 32);
    if (lane < 16) w0buf[wv * 16 + lane] = s0;
    __syncthreads();

    // ---- scatter C (l=1..9) -> dtile ----
    const int qd = lane >> 4, nl = lane & 15;
#pragma unroll
    for (int nt = 1; nt < 10; ++nt)
#pragma unroll
        for (int r = 0; r < 4; ++r)
            dtile[(wv * 16 + qd * 4 + r) * DT2 + (nt - 1) * 16 + nl] = acc[nt][r];
    __syncthreads();

    // ---- scan: wave = chain; lanes = 4 sub-chunks x 16 u ----
    const int sub = (tid >> 4) & 3;
    const int su  = tid & 15;
    const float* dp = dtile + su;
    const int tb = sub * 16;
    float S[10];
#pragma unroll
    for (int i = 0; i < 10; ++i) S[i] = 0.0f;

    float* Lb = L + ((size_t)(b * NTTILE + ttile) * NW) * NU + uq * 16 + su;

    if (wv == 0) {            // chain 1: l=1,2 -> col offs 0,16
        for (int tt = tb; tt < tb + 16; ++tt) {
            const float d1 = dp[tt * DT2 + 0];
            const float d2 = dp[tt * DT2 + 16];
            S[2] += S[0] * d2;
            S[0] += d1;  S[1] += d2;
        }
        wave_fold<3>(S, sub, Chen1());
        if (sub == 0) { Lb[1*NU] = S[0];  Lb[2*NU] = S[1];  Lb[3*NU] = S[2]; }
    } else if (wv == 1) {     // chain 2: l=3,4,5 -> 32,48,64
        for (int tt = tb; tt < tb + 16; ++tt) {
            const float d3 = dp[tt * DT2 + 32];
            const float d4 = dp[tt * DT2 + 48];
            const float d5 = dp[tt * DT2 + 64];
            S[5] += S[3] * d5;
            S[3] += S[0] * d4;
            S[4] += S[1] * d5;
            S[0] += d3;  S[1] += d4;  S[2] += d5;
        }
        wave_fold<6>(S, sub, Chen2());
        if (sub == 0) {
            Lb[4*NU] = S[0];  Lb[5*NU] = S[1];  Lb[6*NU] = S[2];
            Lb[7*NU] = S[3];  Lb[8*NU] = S[4];  Lb[9*NU] = S[5];
        }
    } else if (wv == 2) {     // chain 3: l=6..9 -> 80,96,112,128
        for (int tt = tb; tt < tb + 16; ++tt) {
            const float d6 = dp[tt * DT2 + 80];
            const float d7 = dp[tt * DT2 + 96];
            const float d8 = dp[tt * DT2 + 112];
            const float d9 = dp[tt * DT2 + 128];
            S[9] += S[7] * d9;
            S[7] += S[4] * d8;
            S[8] += S[5] * d9;
            S[4] += S[0] * d7;
            S[5] += S[1] * d8;
            S[6] += S[2] * d9;
            S[0] += d6;  S[1] += d7;  S[2] += d8;  S[3] += d9;
        }
        wave_fold<10>(S, sub, Chen3());
        if (sub == 0) {
            Lb[10*NU] = S[0]; Lb[11*NU] = S[1]; Lb[12*NU] = S[2]; Lb[13*NU] = S[3];
            Lb[14*NU] = S[4]; Lb[15*NU] = S[5]; Lb[16*NU] = S[6];
            Lb[17*NU] = S[7]; Lb[18*NU] = S[8]; Lb[19*NU] = S[9];
        }
    } else {                  // wave 3: finalize word (0)
        if (lane < 16) {
            const float w0 = w0buf[lane] + w0buf[16 + lane] + w0buf[32 + lane] + w0buf[48 + lane];
            Lb[0] = w0;
        }
    }
}

// Kernel 2: fold 32 chunks per b. 8 waves x 4 serial chunks + 3-level LDS tree.
__global__ __launch_bounds__(512)
void k_fold(const float* __restrict__ L, float* __restrict__ out) {
    __shared__ float buf[4][NW][NU];    // 20,480 B
    const int b = blockIdx.x;
    const int u = threadIdx.x & 63;
    const int q = threadIdx.x >> 6;     // 0..7
    const float* Lb = L + (size_t)b * NTTILE * NW * NU + u;

    float E[NW];
    {
        const float* p = Lb + (size_t)(q * 4) * NW * NU;
#pragma unroll
        for (int w = 0; w < NW; ++w) E[w] = p[w * NU];
    }
    for (int c = q * 4 + 1; c < q * 4 + 4; ++c) {
        const float* p = Lb + (size_t)c * NW * NU;
        float Bw[NW], Cw[NW];
#pragma unroll
        for (int w = 0; w < NW; ++w) Bw[w] = p[w * NU];
        chen_combine(E, Bw, Cw);
#pragma unroll
        for (int w = 0; w < NW; ++w) E[w] = Cw[w];
    }

#pragma unroll
    for (int lvl = 0; lvl < 3; ++lvl) {
        const int step = 1 << lvl;
        const bool active = (q & (step - 1)) == 0;
        const bool writer = active && ((q >> lvl) & 1);
        if (writer) {
            const int idx = (q - step) >> (lvl + 1);
#pragma unroll
            for (int w = 0; w < NW; ++w) buf[idx][w][u] = E[w];
        }
        __syncthreads();
        if (active && !writer) {
            const int idx = q >> (lvl + 1);
            float Bw[NW], Cw[NW];
#pragma unroll
            for (int w = 0; w < NW; ++w) Bw[w] = buf[idx][w][u];
            chen_combine(E, Bw, Cw);
#pragma unroll
            for (int w = 0; w < NW; ++w) E[w] = Cw[w];
        }
        __syncthreads();
    }
    if (q == 0) out[b * NU + u] = E[0] + E[3] + E[9] + E[19];
}

extern "C" void kernel_launch(void* const* d_in, const int* in_sizes, int n_in,
                              void* d_out, int out_size, void* d_ws, size_t ws_size,
                              hipStream_t stream) {
    const float* x = (const float*)d_in[0];   // (32, 2048, 63) fp32
    const float* K = (const float*)d_in[1];   // (64, 10, 64)  fp32
    float* out = (float*)d_out;               // (32, 64) fp32
    short* Bg = (short*)d_ws;
    float* L  = (float*)((char*)d_ws + L_OFF);

    k_prep_b<<<8, 256, 0, stream>>>(K, Bg);
    dim3 g1(NTTILE, 4, NB);                   // (32, 4, 32)
    k_gemm_scan<<<g1, 256, 0, stream>>>(x, Bg, L);
    k_fold<<<NB, 512, 0, stream>>>(L, out);
}

// Round 2
// 90.963 us; speedup vs baseline: 1.0071x; 1.0071x over previous
//
#include <hip/hip_runtime.h>

// Problem constants
#define TT     2048
#define NB     32
#define NL     10
#define NU     64
#define TTILE  64
#define NTTILE 32          // TT/TTILE = chunk count after in-block fold
#define NW     20          // iterated-sum words per (b,chunk,u)

// d_ws layout (bytes):
//   Bg: [uq(4)][reg(20)][lane(64)][8] bf16     = 80 KB     @ 0
//   L : [b][chunk(32)][w(20)][u(64)] fp32      = 5.24 MB   @ 128 KB
#define L_OFF  (128u * 1024u)

typedef __attribute__((ext_vector_type(8))) short short8v;   // 8 bf16
typedef __attribute__((ext_vector_type(4))) float float4v;   // MFMA C/D
typedef __attribute__((ext_vector_type(4), aligned(4))) float f4u; // unaligned float4
typedef __attribute__((address_space(3))) char lds_char;
typedef __attribute__((address_space(1))) const char g_char;

__device__ inline short f2bf(float f) {   // RNE float->bf16 raw bits
    unsigned u = __float_as_uint(f);
    u += 0x7fffu + ((u >> 16) & 1u);
    return (short)(u >> 16);
}

// ---- Chen composition (full 20-word alphabet), C = A(earlier) ∘ B(later) ----
// Unified word order (matches L layout):
// 0:(0) | 1:(1) 2:(2) 3:(12) | 4:(3) 5:(4) 6:(5) 7:(34) 8:(45) 9:(345)
// 10:(6) 11:(7) 12:(8) 13:(9) 14:(67) 15:(78) 16:(89) 17:(678) 18:(789) 19:(6789)
__device__ inline void chen_combine(const float* A, const float* B, float* C) {
    C[0]  = A[0] + B[0];
    C[1]  = A[1] + B[1];
    C[2]  = A[2] + B[2];
    C[3]  = A[3] + A[1]*B[2] + B[3];
    C[4]  = A[4] + B[4];
    C[5]  = A[5] + B[5];
    C[6]  = A[6] + B[6];
    C[7]  = A[7] + A[4]*B[5] + B[7];
    C[8]  = A[8] + A[5]*B[6] + B[8];
    C[9]  = A[9] + A[7]*B[6] + A[4]*B[8] + B[9];
    C[10] = A[10] + B[10];
    C[11] = A[11] + B[11];
    C[12] = A[12] + B[12];
    C[13] = A[13] + B[13];
    C[14] = A[14] + A[10]*B[11] + B[14];
    C[15] = A[15] + A[11]*B[12] + B[15];
    C[16] = A[16] + A[12]*B[13] + B[16];
    C[17] = A[17] + A[14]*B[12] + A[10]*B[15] + B[17];
    C[18] = A[18] + A[15]*B[13] + A[11]*B[16] + B[18];
    C[19] = A[19] + A[17]*B[13] + A[14]*B[16] + A[10]*B[18] + B[19];
}

struct Chen20 {
    __device__ void operator()(const float* A, const float* B, float* C) const {
        chen_combine(A, B, C);
    }
};

// Cross-lane fold of 4 sub-chunks (sub = lane>>4) in t-order via xor-16/32 tree.
// After both rounds EVERY lane holds the full 4-chunk combination.
template <int N, typename CH>
__device__ inline void wave_fold(float* S, int sub, CH chen) {
    float O[N], A[N], Bv[N], C[N];
#pragma unroll
    for (int w = 0; w < N; ++w) O[w] = __shfl_xor(S[w], 16);
    {
        const bool e = (sub & 1) == 0;
#pragma unroll
        for (int w = 0; w < N; ++w) { A[w] = e ? S[w] : O[w]; Bv[w] = e ? O[w] : S[w]; }
        chen(A, Bv, C);
    }
#pragma unroll
    for (int w = 0; w < N; ++w) O[w] = __shfl_xor(C[w], 32);
    {
        const bool e = (sub & 2) == 0;
#pragma unroll
        for (int w = 0; w < N; ++w) { A[w] = e ? C[w] : O[w]; Bv[w] = e ? O[w] : C[w]; }
        chen(A, Bv, S);
    }
}

// Kernel 0: K -> bf16 fragment tiles (Bg). 8 blocks.
__global__ __launch_bounds__(256)
void k_prep_b(const float* __restrict__ K, short* __restrict__ Bg) {
    const int tid = threadIdx.x;
    const int kb  = blockIdx.x;                 // 0..7
#pragma unroll
    for (int it = 0; it < 3; ++it) {
        const int r = it * 256 + tid;
        if (r >= 640) break;
        const int idx = kb * 640 + r;           // short8v index 0..5119
        const int lane = idx & 63, r20 = (idx >> 6) % 20, uq = (idx >> 6) / 20;
        const int l = r20 >> 1, s = r20 & 1;
        const int f0 = s * 32 + (lane >> 4) * 8;
        const int u = uq * 16 + (lane & 15);
        short8v v;
#pragma unroll
        for (int j = 0; j < 8; ++j)
            v[j] = f2bf(K[(size_t)(f0 + j) * (NL * NU) + l * NU + u]);
        *(short8v*)(Bg + (size_t)idx * 8) = v;
    }
}

// Kernel 1 (fused): DMA-stage B; build A fragments (dX) in registers from x;
// MFMA d = dX*K; then IN-REGISTER scan: lane nl holds d[t][l][u'=nl] for its
// 4 t-rows (qd*4+r) across all l in acc[nt][r] -- scan 4 t-steps per lane,
// butterfly-fold over qd via wave_fold<20> (word 0 additive), cross-wave fold
// via a 3.75 KB LDS buffer. No dtile scatter, no strided LDS scan.
__global__ __launch_bounds__(256, 4)
void k_gemm_scan(const float* __restrict__ x, const short* __restrict__ Bg,
                 float* __restrict__ L) {
    __shared__ __align__(16) short B_lds[20 * 64 * 8];   // 20,480 B
    __shared__ float fbuf[3][NW][16];                    //  3,840 B

    const int tid   = threadIdx.x;
    const int ttile = blockIdx.x;
    const int uq    = blockIdx.y;
    const int b     = blockIdx.z;
    const int wv    = tid >> 6, lane = tid & 63;
    const int qd    = lane >> 4, nl = lane & 15;

    // ---- async DMA stage: B 20 KB (issued first; latency hides under A build) ----
    {
        const char* gb = (const char*)(Bg + (size_t)uq * 10240);
#pragma unroll
        for (int i = 0; i < 5; ++i) {
            const int e = i * 256 + tid;
            __builtin_amdgcn_global_load_lds((g_char*)(gb + e * 16),
                                             (lds_char*)((char*)B_lds + e * 16), 16, 0, 0);
        }
    }

    // ---- A fragments in registers: dX[t][f] = x[t][f]-x[t-1][f] (f=63 -> dt const) ----
    const int   t      = wv * 16 + nl;
    const int   tb_idx = ttile * TTILE + t;         // time index within batch b
    const int   rowg   = b * TT + tb_idx;           // global row in x
    const int   f0     = qd * 8;                    // s=0 octet: f 0..31
    const int   f1     = 32 + f0;                   // s=1 octet: f 32..63
    const float dtc    = 2.0f / (float)(TT - 1);
    const bool  zrow   = (tb_idx == 0);             // dX row 0 of each batch is zero
    const float* hi = x + (size_t)rowg * 63;
    const float* lo = (rowg == 0) ? hi : hi - 63;   // clamp: b=0,t=0 is zeroed anyway

    short8v a0, a1;
    {
        const f4u h0 = *(const f4u*)(hi + f0);
        const f4u h1 = *(const f4u*)(hi + f0 + 4);
        const f4u l0 = *(const f4u*)(lo + f0);
        const f4u l1 = *(const f4u*)(lo + f0 + 4);
#pragma unroll
        for (int j = 0; j < 4; ++j) { const float d = h0[j] - l0[j]; a0[j]     = f2bf(zrow ? 0.f : d); }
#pragma unroll
        for (int j = 0; j < 4; ++j) { const float d = h1[j] - l1[j]; a0[4 + j] = f2bf(zrow ? 0.f : d); }
    }
    if (f1 == 56) {
        // last octet touches f=63 (time channel, constant dtc); shift the hi load
        // left by 1 so we never read x[rowg*63+63] (OOB at the tensor's last row).
        const f4u h2 = *(const f4u*)(hi + 55);
        const f4u h3 = *(const f4u*)(hi + 59);
        const f4u l2 = *(const f4u*)(lo + 56);
        const f4u l3 = *(const f4u*)(lo + 60);
        float d;
        d = h2[1] - l2[0]; a1[0] = f2bf(zrow ? 0.f : d);
        d = h2[2] - l2[1]; a1[1] = f2bf(zrow ? 0.f : d);
        d = h2[3] - l2[2]; a1[2] = f2bf(zrow ? 0.f : d);
        d = h3[0] - l2[3]; a1[3] = f2bf(zrow ? 0.f : d);
        d = h3[1] - l3[0]; a1[4] = f2bf(zrow ? 0.f : d);
        d = h3[2] - l3[1]; a1[5] = f2bf(zrow ? 0.f : d);
        d = h3[3] - l3[2]; a1[6] = f2bf(zrow ? 0.f : d);
        a1[7] = f2bf(zrow ? 0.f : dtc);
    } else {
        const f4u h2 = *(const f4u*)(hi + f1);
        const f4u h3 = *(const f4u*)(hi + f1 + 4);
        const f4u l2 = *(const f4u*)(lo + f1);
        const f4u l3 = *(const f4u*)(lo + f1 + 4);
#pragma unroll
        for (int j = 0; j < 4; ++j) { const float d = h2[j] - l2[j]; a1[j]     = f2bf(zrow ? 0.f : d); }
#pragma unroll
        for (int j = 0; j < 4; ++j) { const float d = h3[j] - l3[j]; a1[4 + j] = f2bf(zrow ? 0.f : d); }
    }
    __syncthreads();    // drains B DMA (vmcnt(0) before barrier)

    // ---- MFMA: wave wv computes C rows [16wv,16wv+16) x 160 cols ----
    const short8v* B8 = (const short8v*)B_lds;
    float4v acc[10];
#pragma unroll
    for (int nt = 0; nt < 10; ++nt) {
        const short8v b0 = B8[(nt * 2 + 0) * 64 + lane];
        const short8v b1 = B8[(nt * 2 + 1) * 64 + lane];
        float4v z = {0.f, 0.f, 0.f, 0.f};
        z = __builtin_amdgcn_mfma_f32_16x16x32_bf16(a0, b0, z, 0, 0, 0);
        z = __builtin_amdgcn_mfma_f32_16x16x32_bf16(a1, b1, z, 0, 0, 0);
        acc[nt] = z;
    }

    // ---- in-register scan over this lane's 4 t-rows (t = wv*16 + qd*4 + r) ----
    // acc[nt][r] = d[t][l=nt][u = uq*16 + nl]
    float S[NW];
#pragma unroll
    for (int i = 0; i < NW; ++i) S[i] = 0.0f;
    S[0] = acc[0][0] + acc[0][1] + acc[0][2] + acc[0][3];   // word (0): additive

#pragma unroll
    for (int r = 0; r < 4; ++r) {
        const float d1 = acc[1][r], d2 = acc[2][r], d3 = acc[3][r];
        const float d4 = acc[4][r], d5 = acc[5][r], d6 = acc[6][r];
        const float d7 = acc[7][r], d8 = acc[8][r], d9 = acc[9][r];
        // chain 1: S[1..3] = (1),(2),(12)
        S[3]  += S[1]  * d2;
        S[1]  += d1;  S[2] += d2;
        // chain 2: S[4..9] = (3),(4),(5),(34),(45),(345)
        S[9]  += S[7]  * d5;
        S[7]  += S[4]  * d4;
        S[8]  += S[5]  * d5;
        S[4]  += d3;  S[5] += d4;  S[6] += d5;
        // chain 3: S[10..19] = (6),(7),(8),(9),(67),(78),(89),(678),(789),(6789)
        S[19] += S[17] * d9;
        S[17] += S[14] * d8;
        S[18] += S[15] * d9;
        S[14] += S[10] * d7;
        S[15] += S[11] * d8;
        S[16] += S[12] * d9;
        S[10] += d6;  S[11] += d7;  S[12] += d8;  S[13] += d9;
    }

    // ---- fold the 4 qd sub-chunks (each 4 t-steps) within the wave ----
    wave_fold<NW>(S, qd, Chen20());
    // every lane now holds the wave's 16-t-chunk state for column nl

    // ---- cross-wave fold (t-order: wv 0 earliest) ----
    if (wv != 0) {
        if (lane < 16) {
#pragma unroll
            for (int w = 0; w < NW; ++w) fbuf[wv - 1][w][nl] = S[w];
        }
    }
    __syncthreads();

    if (wv == 0 && lane < 16) {
        float E[NW], Bw[NW], Cw[NW];
#pragma unroll
        for (int w = 0; w < NW; ++w) E[w] = S[w];
#pragma unroll
        for (int j = 0; j < 3; ++j) {
#pragma unroll
            for (int w = 0; w < NW; ++w) Bw[w] = fbuf[j][w][nl];
            chen_combine(E, Bw, Cw);
#pragma unroll
            for (int w = 0; w < NW; ++w) E[w] = Cw[w];
        }
        float* Lb = L + ((size_t)(b * NTTILE + ttile) * NW) * NU + uq * 16 + nl;
#pragma unroll
        for (int w = 0; w < NW; ++w) Lb[w * NU] = E[w];
    }
}

// Kernel 2: fold 32 chunks per b. 8 waves x 4 serial chunks + 3-level LDS tree.
__global__ __launch_bounds__(512)
void k_fold(const float* __restrict__ L, float* __restrict__ out) {
    __shared__ float buf[4][NW][NU];    // 20,480 B
    const int b = blockIdx.x;
    const int u = threadIdx.x & 63;
    const int q = threadIdx.x >> 6;     // 0..7
    const float* Lb = L + (size_t)b * NTTILE * NW * NU + u;

    float E[NW];
    {
        const float* p = Lb + (size_t)(q * 4) * NW * NU;
#pragma unroll
        for (int w = 0; w < NW; ++w) E[w] = p[w * NU];
    }
    for (int c = q * 4 + 1; c < q * 4 + 4; ++c) {
        const float* p = Lb + (size_t)c * NW * NU;
        float Bw[NW], Cw[NW];
#pragma unroll
        for (int w = 0; w < NW; ++w) Bw[w] = p[w * NU];
        chen_combine(E, Bw, Cw);
#pragma unroll
        for (int w = 0; w < NW; ++w) E[w] = Cw[w];
    }

#pragma unroll
    for (int lvl = 0; lvl < 3; ++lvl) {
        const int step = 1 << lvl;
        const bool active = (q & (step - 1)) == 0;
        const bool writer = active && ((q >> lvl) & 1);
        if (writer) {
            const int idx = (q - step) >> (lvl + 1);
#pragma unroll
            for (int w = 0; w < NW; ++w) buf[idx][w][u] = E[w];
        }
        __syncthreads();
        if (active && !writer) {
            const int idx = q >> (lvl + 1);
            float Bw[NW], Cw[NW];
#pragma unroll
            for (int w = 0; w < NW; ++w) Bw[w] = buf[idx][w][u];
            chen_combine(E, Bw, Cw);
#pragma unroll
            for (int w = 0; w < NW; ++w) E[w] = Cw[w];
        }
        __syncthreads();
    }
    if (q == 0) out[b * NU + u] = E[0] + E[3] + E[9] + E[19];
}

extern "C" void kernel_launch(void* const* d_in, const int* in_sizes, int n_in,
                              void* d_out, int out_size, void* d_ws, size_t ws_size,
                              hipStream_t stream) {
    const float* x = (const float*)d_in[0];   // (32, 2048, 63) fp32
    const float* K = (const float*)d_in[1];   // (64, 10, 64)  fp32
    float* out = (float*)d_out;               // (32, 64) fp32
    short* Bg = (short*)d_ws;
    float* L  = (float*)((char*)d_ws + L_OFF);

    k_prep_b<<<8, 256, 0, stream>>>(K, Bg);
    dim3 g1(NTTILE, 4, NB);                   // (32, 4, 32)
    k_gemm_scan<<<g1, 256, 0, stream>>>(x, Bg, L);
    k_fold<<<NB, 512, 0, stream>>>(L, out);
}